// Round 1
// baseline (234.890 us; speedup 1.0000x reference)
//
#include <hip/hip_runtime.h>

// GAMSmooth: out[b,l,f] = (X_spline @ kernel)[idx[b,l], f] + bias[f]
// N_UNIQUE=10000, N_BASES=10, FILTERS=16, B=32, L=100000
// Memory-bound: 204.8 MB fp32 output write dominates. Two kernels:
//   1) tiny matmul+bias -> shrunk table in d_ws (640 KB, L2-resident)
//   2) coalesced gather-copy: 4 threads per element, one float4 each.

#define N_UNIQUE 10000
#define N_BASES  10
#define FILTERS  16

__global__ __launch_bounds__(256) void gam_shrunk_kernel(
    const float* __restrict__ X, const float* __restrict__ K,
    const float* __restrict__ bias, float* __restrict__ shrunk) {
  __shared__ float sK[N_BASES * FILTERS];
  __shared__ float sB[FILTERS];
  int t = threadIdx.x;
  if (t < N_BASES * FILTERS) sK[t] = K[t];
  if (t < FILTERS) sB[t] = bias[t];
  __syncthreads();
  int u = blockIdx.x * 256 + t;
  if (u >= N_UNIQUE) return;

  float acc[FILTERS];
#pragma unroll
  for (int f = 0; f < FILTERS; ++f) acc[f] = sB[f];
#pragma unroll
  for (int b = 0; b < N_BASES; ++b) {
    float x = X[u * N_BASES + b];
#pragma unroll
    for (int f = 0; f < FILTERS; ++f) acc[f] += x * sK[b * FILTERS + f];
  }
  float4* dst = (float4*)(shrunk + (size_t)u * FILTERS);
#pragma unroll
  for (int q = 0; q < 4; ++q)
    dst[q] = make_float4(acc[4 * q], acc[4 * q + 1], acc[4 * q + 2], acc[4 * q + 3]);
}

// One float4 per thread; 4 consecutive threads cover one idx element's 16
// filters -> consecutive lanes store consecutive 16B (perfect coalescing).
__global__ __launch_bounds__(256) void gam_gather_kernel(
    const int* __restrict__ idx, const float4* __restrict__ shrunk4,
    float4* __restrict__ out4, int total4) {
  int gid = blockIdx.x * 256 + threadIdx.x;
  if (gid >= total4) return;
  int e = gid >> 2;          // which (b,l) element
  int q = gid & 3;           // which float4 of the 16-filter row
  int u = idx[e];            // 4 lanes share this load (same cacheline)
  out4[gid] = shrunk4[(size_t)u * 4 + q];
}

extern "C" void kernel_launch(void* const* d_in, const int* in_sizes, int n_in,
                              void* d_out, int out_size, void* d_ws, size_t ws_size,
                              hipStream_t stream) {
  const int*   idx  = (const int*)d_in[0];    // [B, L]
  const float* X    = (const float*)d_in[1];  // [N_UNIQUE, N_BASES]
  const float* K    = (const float*)d_in[2];  // [N_BASES, FILTERS]
  const float* bias = (const float*)d_in[3];  // [FILTERS]
  float* out    = (float*)d_out;              // [B, L, FILTERS] fp32
  float* shrunk = (float*)d_ws;               // 10000*16 fp32 = 640 KB

  // Kernel 1: shrunk = X @ K + bias  (d_ws is re-poisoned every launch, so
  // this must run on every call — it's ~2 us).
  gam_shrunk_kernel<<<(N_UNIQUE + 255) / 256, 256, 0, stream>>>(X, K, bias, shrunk);

  // Kernel 2: coalesced gather.
  int n_elem = in_sizes[0];                   // B*L = 3,200,000
  long long total4ll = (long long)n_elem * 4; // 12,800,000 float4 stores
  int total4 = (int)total4ll;
  int blocks = (int)((total4ll + 255) / 256);
  gam_gather_kernel<<<blocks, 256, 0, stream>>>(idx, (const float4*)shrunk,
                                                (float4*)out, total4);
}